// Round 5
// baseline (761.554 us; speedup 1.0000x reference)
//
#include <hip/hip_runtime.h>

#define N_NODES 50000
#define N_EDGES 800000
#define D_IN    128
#define D_E     64
#define NH      4
#define F_TOT   128          // NH * D_OUT
#define NEG_SLOPE 0.2f

typedef __attribute__((ext_vector_type(8))) short short8;   // 8 bf16
typedef __attribute__((ext_vector_type(4))) float f32x4;

__device__ __forceinline__ short f2bf(float x) {            // RNE f32->bf16
    unsigned u = __float_as_uint(x);
    u += 0x7FFFu + ((u >> 16) & 1u);
    return (short)(u >> 16);
}

// ---------------------------------------------------------------------------
// K1: fused hist + node transform.
//   part A: deg histogram (grid-stride over edges; independent of part B)
//   part B: HT[n][f] = sum_k H[n][k] * W[f][k]   (fp32 -> workspace)
// ---------------------------------------------------------------------------
__global__ __launch_bounds__(256) void k_pre(
    const float* __restrict__ H, const float* __restrict__ W,
    float* __restrict__ HT, const int* __restrict__ EI,
    int* __restrict__ deg)
{
    const int tid = threadIdx.x;
    // part A: histogram
    for (int e = blockIdx.x * 256 + tid; e < N_EDGES; e += gridDim.x * 256)
        atomicAdd(&deg[EI[N_EDGES + e]], 1);

    // part B: node transform
    __shared__ float wt[D_IN * F_TOT];   // wt[k*128+f] = W[f][k]
    for (int i = tid; i < D_IN * F_TOT; i += 256) {
        const int f = i & 127, k = i >> 7;
        wt[k * F_TOT + f] = W[f * D_IN + k];
    }
    __syncthreads();

    const int l = tid & 63;
    const int w = tid >> 6;
    const int gwave  = blockIdx.x * 4 + w;
    const int nwaves = gridDim.x * 4;
    const int ngroups = N_NODES / 8;     // 6250, exact

    for (int grp = gwave; grp < ngroups; grp += nwaves) {
        const int g = grp * 8;
        float ax[8], ay[8];
#pragma unroll
        for (int j = 0; j < 8; ++j) { ax[j] = 0.f; ay[j] = 0.f; }

        for (int k4 = 0; k4 < D_IN / 4; ++k4) {
            float hv[8][4];
#pragma unroll
            for (int j = 0; j < 8; ++j)
                *(float4*)hv[j] = *(const float4*)&H[(size_t)(g + j) * D_IN + k4 * 4];
#pragma unroll
            for (int kk = 0; kk < 4; ++kk) {
                const float2 wk = *(const float2*)&wt[(k4 * 4 + kk) * F_TOT + 2 * l];
#pragma unroll
                for (int j = 0; j < 8; ++j) {
                    ax[j] = fmaf(wk.x, hv[j][kk], ax[j]);
                    ay[j] = fmaf(wk.y, hv[j][kk], ay[j]);
                }
            }
        }
#pragma unroll
        for (int j = 0; j < 8; ++j) {
            float2 r; r.x = ax[j]; r.y = ay[j];
            *(float2*)&HT[(size_t)(g + j) * F_TOT + 2 * l] = r;
        }
    }
}

// ---------------------------------------------------------------------------
// K2: single-block exclusive scan, 4 nodes/thread (13 iters, was 49) and
// shfl-based second level (was: TWO serial 16-step LDS loops ~3.7k dep cycles
// per iteration on ONE CU — the hidden ~90us suspect).
// ---------------------------------------------------------------------------
__global__ __launch_bounds__(1024) void k_scan(
    const int* __restrict__ deg, int* __restrict__ row_start,
    int* __restrict__ cursor)
{
    __shared__ int wsum[16];
    __shared__ int carry;
    const int tid = threadIdx.x;
    const int l = tid & 63;
    const int wv = tid >> 6;
    if (tid == 0) carry = 0;

    const int4* deg4 = (const int4*)deg;
    const int N4 = N_NODES / 4;                 // 12500, exact

    for (int base = 0; base < N4; base += 1024) {
        __syncthreads();                        // [A] carry ready, wsum free
        const int cb = carry;
        const int i4 = base + tid;
        int4 d = make_int4(0, 0, 0, 0);
        if (i4 < N4) d = deg4[i4];
        const int t0 = d.x, t1 = t0 + d.y, t2 = t1 + d.z, t3 = t2 + d.w;
        int x = t3;                             // wave inclusive scan of t3
#pragma unroll
        for (int off = 1; off < 64; off <<= 1) {
            int t = __shfl_up(x, off, 64);
            if (l >= off) x += t;
        }
        if (l == 63) wsum[wv] = x;
        __syncthreads();                        // [B] wsum ready
        // parallel second level: every wave redundantly scans wsum[0..15]
        int s = (l < 16) ? wsum[l] : 0;
#pragma unroll
        for (int off = 1; off < 16; off <<= 1) {
            int t = __shfl_up(s, off, 64);
            if (l >= off) s += t;
        }
        const int tot      = __shfl(s, 15, 64);
        const int wave_off = (wv == 0) ? 0 : __shfl(s, wv - 1, 64);
        const int excl     = cb + wave_off + (x - t3);
        if (i4 < N4) {
            int4 rs;
            rs.x = excl; rs.y = excl + t0; rs.z = excl + t1; rs.w = excl + t2;
            ((int4*)row_start)[i4] = rs;
            ((int4*)cursor)[i4]    = rs;
        }
        if (tid == 0) carry = cb + tot;         // after [B]; visible at next [A]
    }
    __syncthreads();
    if (tid == 0) row_start[N_NODES] = carry;
}

// ---------------------------------------------------------------------------
// K3: CSR permutation build. perm[pos] = {eid, src}, pos from cursor atomic.
// ---------------------------------------------------------------------------
__global__ __launch_bounds__(256) void k_permute(
    const int* __restrict__ EI, int* __restrict__ cursor,
    int2* __restrict__ perm)
{
    const int e = blockIdx.x * 256 + threadIdx.x;
    if (e < N_EDGES) {
        const int src = EI[e];
        const int dst = EI[N_EDGES + e];
        const int pos = atomicAdd(&cursor[dst], 1);
        perm[pos] = make_int2(e, src);
    }
}

// ---------------------------------------------------------------------------
// K4: FUSED logits + aggregation. One wave per dst node, grid-stride,
// 2-tile software pipeline (R5): all global loads for tiles A and B issued
// before any conversion/compute consumes them -> ~2x memory-level
// parallelism per wave (the R4 kernel was serial per tile:
// perm -> gathers -> compute, ~20 waves' worth of latency, only 16 resident).
//   Per 16-edge CSR tile (lane-per-edge layout, operand-swapped MFMA):
//     D(16f x 16e) = We_tile(16f x 32k) @ E_tile^T(32k x 16e)
//     D: col=lane&15 -> EDGE (CSR slot), row=(lane>>4)*4+reg -> feature
// ---------------------------------------------------------------------------

// issue raw global loads for one tile (no waits consumed here)
#define TILE_LOADRAW(PE, HS, E0, E1, E2, E3)                                  \
    {                                                                         \
        const float* hsp_ = &HT[(size_t)(PE).y * F_TOT + g4 * 4];             \
        _Pragma("unroll")                                                     \
        for (int ft = 0; ft < 8; ++ft)                                        \
            HS[ft] = *(const f32x4*)(hsp_ + ft * 16);                         \
        const float* ep_ = &E[(size_t)(PE).x * D_E + g4 * 8];                 \
        E0 = *(const f32x4*)ep_;                                              \
        E1 = *(const f32x4*)(ep_ + 4);                                        \
        E2 = *(const f32x4*)(ep_ + 32);                                       \
        E3 = *(const f32x4*)(ep_ + 36);                                       \
    }

#define TILE_CONV(E0, E1, E2, E3, AF)                                         \
    {                                                                         \
        short8 a_;                                                            \
        a_[0]=f2bf(E0[0]); a_[1]=f2bf(E0[1]); a_[2]=f2bf(E0[2]); a_[3]=f2bf(E0[3]); \
        a_[4]=f2bf(E1[0]); a_[5]=f2bf(E1[1]); a_[6]=f2bf(E1[2]); a_[7]=f2bf(E1[3]); \
        AF[0] = a_;                                                           \
        a_[0]=f2bf(E2[0]); a_[1]=f2bf(E2[1]); a_[2]=f2bf(E2[2]); a_[3]=f2bf(E2[3]); \
        a_[4]=f2bf(E3[0]); a_[5]=f2bf(E3[1]); a_[6]=f2bf(E3[2]); a_[7]=f2bf(E3[3]); \
        AF[1] = a_;                                                           \
    }

#define TILE_COMPUTE(HS, AF, VMASK)                                           \
    {                                                                         \
        float ph_[4] = {0.f, 0.f, 0.f, 0.f};                                  \
        _Pragma("unroll")                                                     \
        for (int ft = 0; ft < 8; ++ft) {                                      \
            f32x4 z_ = {0.f, 0.f, 0.f, 0.f};                                  \
            z_ = __builtin_amdgcn_mfma_f32_16x16x32_bf16(s_bf[ft][0][l], AF[0], z_, 0, 0, 0); \
            const f32x4 acc_ =                                                \
                __builtin_amdgcn_mfma_f32_16x16x32_bf16(s_bf[ft][1][l], AF[1], z_, 0, 0, 0);  \
            const f32x4 at_ = s_att[ft][g4];                                  \
            const f32x4 hd_ = s_hd[wv][ft][g4];                               \
            _Pragma("unroll")                                                 \
            for (int r = 0; r < 4; ++r) {                                     \
                float v_ = HS[ft][r] + hd_[r] + acc_[r];                      \
                v_ = v_ > 0.f ? v_ : NEG_SLOPE * v_;                          \
                ph_[ft >> 1] = fmaf(v_, at_[r], ph_[ft >> 1]);                \
            }                                                                 \
        }                                                                     \
        _Pragma("unroll")                                                     \
        for (int h = 0; h < 4; ++h) {                                         \
            ph_[h] += __shfl_xor(ph_[h], 16, 64);                             \
            ph_[h] += __shfl_xor(ph_[h], 32, 64);                             \
        }                                                                     \
        float w4_[4];                                                         \
        _Pragma("unroll")                                                     \
        for (int h = 0; h < 4; ++h) {                                         \
            w4_[h] = (VMASK) ? __expf(ph_[h]) : 0.f;                          \
            sw[h] += w4_[h];                                                  \
        }                                                                     \
        _Pragma("unroll")                                                     \
        for (int ft = 0; ft < 8; ++ft) {                                      \
            const float wh_ = w4_[ft >> 1];                                   \
            _Pragma("unroll")                                                 \
            for (int r = 0; r < 4; ++r)                                       \
                am[ft][r] = fmaf(wh_, HS[ft][r], am[ft][r]);                  \
        }                                                                     \
    }

__global__ __launch_bounds__(256, 2) void k_fused(
    const float* __restrict__ E, const float* __restrict__ We,
    const float* __restrict__ att, const float* __restrict__ HT,
    const int2* __restrict__ perm, const int* __restrict__ row_start,
    float* __restrict__ out)
{
    __shared__ short8 s_bf[8][2][64];   // 16 KB: per-lane We fragments (bf16)
    __shared__ f32x4  s_att[8][4];      // 512 B
    __shared__ f32x4  s_hd[4][8][4];    // 2 KB: dst-row fragments, per wave

    const int tid = threadIdx.x;
    const int l   = tid & 63;
    const int wv  = tid >> 6;
    const int r16 = l & 15;          // edge slot within tile
    const int g4  = l >> 4;          // feature group / k-chunk selector

    if (wv == 0) {
#pragma unroll
        for (int ft = 0; ft < 8; ++ft) {
#pragma unroll
            for (int kc = 0; kc < 2; ++kc) {
                const float* wp = &We[(size_t)(ft * 16 + r16) * D_E + kc * 32 + g4 * 8];
                const f32x4 lo = *(const f32x4*)wp;
                const f32x4 hi = *(const f32x4*)(wp + 4);
                short8 b;
                b[0] = f2bf(lo[0]); b[1] = f2bf(lo[1]); b[2] = f2bf(lo[2]); b[3] = f2bf(lo[3]);
                b[4] = f2bf(hi[0]); b[5] = f2bf(hi[1]); b[6] = f2bf(hi[2]); b[7] = f2bf(hi[3]);
                s_bf[ft][kc][l] = b;
            }
        }
        if (l < 32) {
            const int ft = l >> 2, g = l & 3;
            s_att[ft][g] = *(const f32x4*)&att[ft * 16 + g * 4];
        }
    }
    __syncthreads();

    const int gw      = blockIdx.x * 4 + wv;
    const int gstride = gridDim.x * 4;

    for (int n = gw; n < N_NODES; n += gstride) {
        const int beg = row_start[n];
        const int end = row_start[n + 1];

        // dst row -> LDS (512 B/wave); same-wave produce/consume (lgkmcnt)
        if (l < 32)
            s_hd[wv][l >> 2][l & 3] = *(const f32x4*)&HT[(size_t)n * F_TOT + l * 4];

        f32x4 am[8];
#pragma unroll
        for (int ft = 0; ft < 8; ++ft) am[ft] = (f32x4){0.f, 0.f, 0.f, 0.f};
        float sw[4] = {0.f, 0.f, 0.f, 0.f};

        for (int t = beg; t < end; t += 32) {
            const int  iA = t + r16;
            const bool vA = iA < end;
            const int2 peA = perm[vA ? iA : end - 1];
            const bool anyB = (t + 16) < end;

            f32x4 hsA[8], eA0, eA1, eA2, eA3;
            short8 afA[2];
            f32x4 hsB[8], eB0, eB1, eB2, eB3;
            short8 afB[2];
            int2 peB;

            TILE_LOADRAW(peA, hsA, eA0, eA1, eA2, eA3);
            if (anyB) {
                const int  iB = t + 16 + r16;
                const bool vB_ = iB < end;
                peB = perm[vB_ ? iB : end - 1];
                TILE_LOADRAW(peB, hsB, eB0, eB1, eB2, eB3);
            }

            TILE_CONV(eA0, eA1, eA2, eA3, afA);
            TILE_COMPUTE(hsA, afA, vA);

            if (anyB) {
                const bool vB = (t + 16 + r16) < end;
                TILE_CONV(eB0, eB1, eB2, eB3, afB);
                TILE_COMPUTE(hsB, afB, vB);
            }
        }

        // reduce over the 16 edge-lanes (masks 1..8 stay inside g4 group)
#pragma unroll
        for (int m = 1; m < 16; m <<= 1) {
#pragma unroll
            for (int h = 0; h < 4; ++h) sw[h] += __shfl_xor(sw[h], m, 64);
#pragma unroll
            for (int ft = 0; ft < 8; ++ft)
#pragma unroll
                for (int r = 0; r < 4; ++r)
                    am[ft][r] += __shfl_xor(am[ft][r], m, 64);
        }
        float inv[4];
#pragma unroll
        for (int h = 0; h < 4; ++h) inv[h] = 1.f / (sw[h] + 1e-16f);

        if (r16 == 0) {                 // 4 lanes store 32 features each
#pragma unroll
            for (int ft = 0; ft < 8; ++ft) {
                f32x4 o;
#pragma unroll
                for (int r = 0; r < 4; ++r) o[r] = am[ft][r] * inv[ft >> 1];
                *(f32x4*)&out[(size_t)n * F_TOT + ft * 16 + g4 * 4] = o;
            }
        }
    }
}

extern "C" void kernel_launch(void* const* d_in, const int* in_sizes, int n_in,
                              void* d_out, int out_size, void* d_ws, size_t ws_size,
                              hipStream_t stream)
{
    const float* H   = (const float*)d_in[0];
    const int*   EI  = (const int*)d_in[1];
    const float* E   = (const float*)d_in[2];
    const float* W   = (const float*)d_in[3];
    const float* We  = (const float*)d_in[4];
    const float* att = (const float*)d_in[5];
    float* out = (float*)d_out;

    // workspace layout (~33 MB); all segments 16B-aligned
    float* HT        = (float*)d_ws;                          // 6.4M f32
    int2*  perm      = (int2*)(HT + (size_t)N_NODES * F_TOT); // 800k int2
    int*   deg       = (int*)(perm + N_EDGES);                // 50k
    int*   row_start = deg + N_NODES;                         // 50004 (padded)
    int*   cursor    = row_start + N_NODES + 4;               // 50k

    hipMemsetAsync(deg, 0, N_NODES * sizeof(int), stream);

    k_pre<<<512, 256, 0, stream>>>(H, W, HT, EI, deg);
    k_scan<<<1, 1024, 0, stream>>>(deg, row_start, cursor);
    k_permute<<<(N_EDGES + 255) / 256, 256, 0, stream>>>(EI, cursor, perm);
    k_fused<<<1024, 256, 0, stream>>>(E, We, att, HT, perm, row_start, out);
}

// Round 7
// 560.741 us; speedup vs baseline: 1.3581x; 1.3581x over previous
//
#include <hip/hip_runtime.h>

#define N_NODES 50000
#define N_EDGES 800000
#define D_IN    128
#define D_E     64
#define NH      4
#define F_TOT   128          // NH * D_OUT
#define NEG_SLOPE 0.2f

typedef __attribute__((ext_vector_type(8))) short short8;   // 8 bf16
typedef __attribute__((ext_vector_type(4))) float f32x4;

__device__ __forceinline__ short f2bf(float x) {            // RNE f32->bf16
    unsigned u = __float_as_uint(x);
    u += 0x7FFFu + ((u >> 16) & 1u);
    return (short)(u >> 16);
}

__device__ __forceinline__ int rfl(int x) {
    return __builtin_amdgcn_readfirstlane(x);
}

// ---------------------------------------------------------------------------
// K1: fused hist + node transform.
// ---------------------------------------------------------------------------
__global__ __launch_bounds__(256) void k_pre(
    const float* __restrict__ H, const float* __restrict__ W,
    float* __restrict__ HT, const int* __restrict__ EI,
    int* __restrict__ deg)
{
    const int tid = threadIdx.x;
    for (int e = blockIdx.x * 256 + tid; e < N_EDGES; e += gridDim.x * 256)
        atomicAdd(&deg[EI[N_EDGES + e]], 1);

    __shared__ float wt[D_IN * F_TOT];   // wt[k*128+f] = W[f][k]
    for (int i = tid; i < D_IN * F_TOT; i += 256) {
        const int f = i & 127, k = i >> 7;
        wt[k * F_TOT + f] = W[f * D_IN + k];
    }
    __syncthreads();

    const int l = tid & 63;
    const int w = tid >> 6;
    const int gwave  = blockIdx.x * 4 + w;
    const int nwaves = gridDim.x * 4;
    const int ngroups = N_NODES / 8;     // 6250, exact

    for (int grp = gwave; grp < ngroups; grp += nwaves) {
        const int g = grp * 8;
        float ax[8], ay[8];
#pragma unroll
        for (int j = 0; j < 8; ++j) { ax[j] = 0.f; ay[j] = 0.f; }

        for (int k4 = 0; k4 < D_IN / 4; ++k4) {
            float hv[8][4];
#pragma unroll
            for (int j = 0; j < 8; ++j)
                *(float4*)hv[j] = *(const float4*)&H[(size_t)(g + j) * D_IN + k4 * 4];
#pragma unroll
            for (int kk = 0; kk < 4; ++kk) {
                const float2 wk = *(const float2*)&wt[(k4 * 4 + kk) * F_TOT + 2 * l];
#pragma unroll
                for (int j = 0; j < 8; ++j) {
                    ax[j] = fmaf(wk.x, hv[j][kk], ax[j]);
                    ay[j] = fmaf(wk.y, hv[j][kk], ay[j]);
                }
            }
        }
#pragma unroll
        for (int j = 0; j < 8; ++j) {
            float2 r; r.x = ax[j]; r.y = ay[j];
            *(float2*)&HT[(size_t)(g + j) * F_TOT + 2 * l] = r;
        }
    }
}

// ---------------------------------------------------------------------------
// K2: single-block exclusive scan (int4 + shfl second level)
// ---------------------------------------------------------------------------
__global__ __launch_bounds__(1024) void k_scan(
    const int* __restrict__ deg, int* __restrict__ row_start,
    int* __restrict__ cursor)
{
    __shared__ int wsum[16];
    __shared__ int carry;
    const int tid = threadIdx.x;
    const int l = tid & 63;
    const int wv = tid >> 6;
    if (tid == 0) carry = 0;

    const int4* deg4 = (const int4*)deg;
    const int N4 = N_NODES / 4;                 // 12500, exact

    for (int base = 0; base < N4; base += 1024) {
        __syncthreads();
        const int cb = carry;
        const int i4 = base + tid;
        int4 d = make_int4(0, 0, 0, 0);
        if (i4 < N4) d = deg4[i4];
        const int t0 = d.x, t1 = t0 + d.y, t2 = t1 + d.z, t3 = t2 + d.w;
        int x = t3;
#pragma unroll
        for (int off = 1; off < 64; off <<= 1) {
            int t = __shfl_up(x, off, 64);
            if (l >= off) x += t;
        }
        if (l == 63) wsum[wv] = x;
        __syncthreads();
        int s = (l < 16) ? wsum[l] : 0;
#pragma unroll
        for (int off = 1; off < 16; off <<= 1) {
            int t = __shfl_up(s, off, 64);
            if (l >= off) s += t;
        }
        const int tot      = __shfl(s, 15, 64);
        const int wave_off = (wv == 0) ? 0 : __shfl(s, wv - 1, 64);
        const int excl     = cb + wave_off + (x - t3);
        if (i4 < N4) {
            int4 rs;
            rs.x = excl; rs.y = excl + t0; rs.z = excl + t1; rs.w = excl + t2;
            ((int4*)row_start)[i4] = rs;
            ((int4*)cursor)[i4]    = rs;
        }
        if (tid == 0) carry = cb + tot;
    }
    __syncthreads();
    if (tid == 0) row_start[N_NODES] = carry;
}

// ---------------------------------------------------------------------------
// K3: CSR permutation build.
// ---------------------------------------------------------------------------
__global__ __launch_bounds__(256) void k_permute(
    const int* __restrict__ EI, int* __restrict__ cursor,
    int2* __restrict__ perm)
{
    const int e = blockIdx.x * 256 + threadIdx.x;
    if (e < N_EDGES) {
        const int src = EI[e];
        const int dst = EI[N_EDGES + e];
        const int pos = atomicAdd(&cursor[dst], 1);
        perm[pos] = make_int2(e, src);
    }
}

// ---------------------------------------------------------------------------
// K4: FUSED logits + aggregation, CROSS-NODE software pipeline (R6/R7).
//   3-deep tile-stream cursor across node boundaries:
//     c0 = tile being computed (ev/hsv arrived)
//     c1 = tile whose ev/hsv are issued THIS iteration (pe1v arrived)
//     c2 = tile whose perm entry is in flight (pe2v)
//   Buffers reissued immediately after their last consumer. Node epilogue
//   (reduce+store) covers cross-node load latency. Cursor scalars in SGPRs
//   via readfirstlane. Numerics identical to R4.
//   R7 hardening: hard iteration bound (legit max ~50013/wave) — converts
//   any unforeseen cursor bug from a container-killing hang into a visible
//   wrong-answer.
// ---------------------------------------------------------------------------
__global__ __launch_bounds__(256, 2) void k_fused(
    const float* __restrict__ E, const float* __restrict__ We,
    const float* __restrict__ att, const float* __restrict__ HT,
    const int2* __restrict__ perm, const int* __restrict__ row_start,
    float* __restrict__ out)
{
    __shared__ short8 s_bf[8][2][64];   // 16 KB: per-lane We fragments (bf16)
    __shared__ f32x4  s_att[8][4];      // 512 B
    __shared__ f32x4  s_hd[4][8][4];    // 2 KB: dst-row fragments, per wave

    const int tid = threadIdx.x;
    const int l   = tid & 63;
    const int wv  = tid >> 6;
    const int r16 = l & 15;          // edge slot within tile
    const int g4  = l >> 4;          // feature group / k-chunk selector

    if (wv == 0) {
#pragma unroll
        for (int ft = 0; ft < 8; ++ft) {
#pragma unroll
            for (int kc = 0; kc < 2; ++kc) {
                const float* wp = &We[(size_t)(ft * 16 + r16) * D_E + kc * 32 + g4 * 8];
                const f32x4 lo = *(const f32x4*)wp;
                const f32x4 hi = *(const f32x4*)(wp + 4);
                short8 b;
                b[0] = f2bf(lo[0]); b[1] = f2bf(lo[1]); b[2] = f2bf(lo[2]); b[3] = f2bf(lo[3]);
                b[4] = f2bf(hi[0]); b[5] = f2bf(hi[1]); b[6] = f2bf(hi[2]); b[7] = f2bf(hi[3]);
                s_bf[ft][kc][l] = b;
            }
        }
        if (l < 32) {
            const int ft = l >> 2, g = l & 3;
            s_att[ft][g] = *(const f32x4*)&att[ft * 16 + g * 4];
        }
    }
    __syncthreads();

    const int gs = rfl(gridDim.x * 4);

    // ---- cursor construction (wave-uniform scalars) ----
    int n0 = rfl(blockIdx.x * 4 + wv);
    int t0 = rfl(row_start[n0]);
    int e0 = rfl(row_start[n0 + 1]);

    int n1 = n0, t1, e1;
    if (t0 + 16 < e0) { t1 = t0 + 16; e1 = e0; }
    else {
        n1 = n0 + gs;
        if (n1 < N_NODES) { t1 = rfl(row_start[n1]); e1 = rfl(row_start[n1 + 1]); }
        else { t1 = 0; e1 = 0; }
    }
    int n2 = n1, t2, e2;
    if (t1 + 16 < e1) { t2 = t1 + 16; e2 = e1; }
    else if (n1 < N_NODES) {
        n2 = n1 + gs;
        if (n2 < N_NODES) { t2 = rfl(row_start[n2]); e2 = rfl(row_start[n2 + 1]); }
        else { t2 = 0; e2 = 0; }
    } else { t2 = 0; e2 = 0; }

    int nN = n2 + gs;                   // next-node preload
    int bN = 0, eN = 0;
    if (nN < N_NODES) { bN = rfl(row_start[nN]); eN = rfl(row_start[nN + 1]); }

#define PCLAMP(T, EE) (max(min((T) + r16, (EE) - 1), 0))

    // ---- pipeline prologue ----
    int2 pe0v = perm[PCLAMP(t0, e0)];
    int2 pe1v = perm[PCLAMP(t1, e1)];
    int2 pe2v = perm[PCLAMP(t2, e2)];

    f32x4 ev0, ev1, ev2, ev3;
    {
        const float* ep = &E[(size_t)pe0v.x * D_E + g4 * 8];
        ev0 = *(const f32x4*)ep;       ev1 = *(const f32x4*)(ep + 4);
        ev2 = *(const f32x4*)(ep + 32); ev3 = *(const f32x4*)(ep + 36);
    }
    f32x4 hsv[8];
    {
        const float* hp = &HT[(size_t)pe0v.y * F_TOT + g4 * 4];
#pragma unroll
        for (int ft = 0; ft < 8; ++ft) hsv[ft] = *(const f32x4*)(hp + ft * 16);
    }
    if (l < 32 && n0 < N_NODES)
        s_hd[wv][l >> 2][l & 3] = *(const f32x4*)&HT[(size_t)n0 * F_TOT + l * 4];

    f32x4 am[8];
#pragma unroll
    for (int ft = 0; ft < 8; ++ft) am[ft] = (f32x4){0.f, 0.f, 0.f, 0.f};
    float sw[4] = {0.f, 0.f, 0.f, 0.f};
    f32x4 hdld = (f32x4){0.f, 0.f, 0.f, 0.f};

    int safety = 65536;                 // hard bound: legit max ~50013
    while (n0 < N_NODES && safety-- > 0) {
        // A: c2' = advance(c2); refresh next-node preload on crossing
        int n2n = n2, t2n = t2, e2n = e2;
        if (t2 + 16 < e2) { t2n = t2 + 16; }
        else if (n2 < N_NODES) {
            n2n = nN;
            if (nN < N_NODES) { t2n = bN; e2n = eN; } else { t2n = 0; e2n = 0; }
            nN += gs;
            if (nN < N_NODES) { bN = rfl(row_start[nN]); eN = rfl(row_start[nN + 1]); }
        }
        // B: issue perm for c2' (consumed 2 iterations from now)
        int2 peT = perm[PCLAMP(t2n, e2n)];
        // C: hd prefetch for n1's node (consumed next iteration)
        if (l < 32 && n1 < N_NODES)
            hdld = *(const f32x4*)&HT[(size_t)n1 * F_TOT + l * 4];

        // D: conv ev -> af (waits ev; ev regs dead after)
        short8 af0, af1;
        af0[0]=f2bf(ev0[0]); af0[1]=f2bf(ev0[1]); af0[2]=f2bf(ev0[2]); af0[3]=f2bf(ev0[3]);
        af0[4]=f2bf(ev1[0]); af0[5]=f2bf(ev1[1]); af0[6]=f2bf(ev1[2]); af0[7]=f2bf(ev1[3]);
        af1[0]=f2bf(ev2[0]); af1[1]=f2bf(ev2[1]); af1[2]=f2bf(ev2[2]); af1[3]=f2bf(ev2[3]);
        af1[4]=f2bf(ev3[0]); af1[5]=f2bf(ev3[1]); af1[6]=f2bf(ev3[2]); af1[7]=f2bf(ev3[3]);
        // E: reissue ev for c1 (in flight through rest of this iter + next conv)
        {
            const float* ep = &E[(size_t)pe1v.x * D_E + g4 * 8];
            ev0 = *(const f32x4*)ep;       ev1 = *(const f32x4*)(ep + 4);
            ev2 = *(const f32x4*)(ep + 32); ev3 = *(const f32x4*)(ep + 36);
        }

        // F: MFMA + logit partial (hsv arrived: issued last iteration)
        float ph[4] = {0.f, 0.f, 0.f, 0.f};
#pragma unroll
        for (int ft = 0; ft < 8; ++ft) {
            f32x4 z = {0.f, 0.f, 0.f, 0.f};
            z = __builtin_amdgcn_mfma_f32_16x16x32_bf16(s_bf[ft][0][l], af0, z, 0, 0, 0);
            const f32x4 acc =
                __builtin_amdgcn_mfma_f32_16x16x32_bf16(s_bf[ft][1][l], af1, z, 0, 0, 0);
            const f32x4 at = s_att[ft][g4];
            const f32x4 hd = s_hd[wv][ft][g4];
#pragma unroll
            for (int r = 0; r < 4; ++r) {
                float v = hsv[ft][r] + hd[r] + acc[r];
                v = v > 0.f ? v : NEG_SLOPE * v;
                ph[ft >> 1] = fmaf(v, at[r], ph[ft >> 1]);
            }
        }
        // G: cross-lane logit reduce + softmax weight
        const bool valid = (t0 + r16) < e0;
#pragma unroll
        for (int h = 0; h < 4; ++h) {
            ph[h] += __shfl_xor(ph[h], 16, 64);
            ph[h] += __shfl_xor(ph[h], 32, 64);
        }
        float w[4];
#pragma unroll
        for (int h = 0; h < 4; ++h) {
            w[h] = valid ? __expf(ph[h]) : 0.f;
            sw[h] += w[h];
        }
        // H: message accumulation (last consumer of hsv)
#pragma unroll
        for (int ft = 0; ft < 8; ++ft) {
            const float wh = w[ft >> 1];
#pragma unroll
            for (int r = 0; r < 4; ++r)
                am[ft][r] = fmaf(wh, hsv[ft][r], am[ft][r]);
        }
        // I: reissue hsv for c1
        {
            const float* hp = &HT[(size_t)pe1v.y * F_TOT + g4 * 4];
#pragma unroll
            for (int ft = 0; ft < 8; ++ft) hsv[ft] = *(const f32x4*)(hp + ft * 16);
        }

        // J: node boundary — epilogue covers the just-issued loads
        if (n1 != n0) {
#pragma unroll
            for (int m = 1; m < 16; m <<= 1) {
#pragma unroll
                for (int h = 0; h < 4; ++h) sw[h] += __shfl_xor(sw[h], m, 64);
#pragma unroll
                for (int ft = 0; ft < 8; ++ft)
#pragma unroll
                    for (int r = 0; r < 4; ++r)
                        am[ft][r] += __shfl_xor(am[ft][r], m, 64);
            }
            float inv[4];
#pragma unroll
            for (int h = 0; h < 4; ++h) inv[h] = 1.f / (sw[h] + 1e-16f);
            if (r16 == 0) {
#pragma unroll
                for (int ft = 0; ft < 8; ++ft) {
                    f32x4 o;
#pragma unroll
                    for (int r = 0; r < 4; ++r) o[r] = am[ft][r] * inv[ft >> 1];
                    *(f32x4*)&out[(size_t)n0 * F_TOT + ft * 16 + g4 * 4] = o;
                }
            }
#pragma unroll
            for (int ft = 0; ft < 8; ++ft) am[ft] = (f32x4){0.f, 0.f, 0.f, 0.f};
            sw[0] = sw[1] = sw[2] = sw[3] = 0.f;
        }
        // s_hd update for n1 (after F read n0's copy; safe when n1==n0: same data)
        if (l < 32) s_hd[wv][l >> 2][l & 3] = hdld;

        // K: rotate cursors and perm registers
        n0 = n1; t0 = t1; e0 = e1;
        n1 = n2; t1 = t2; e1 = e2;
        n2 = n2n; t2 = t2n; e2 = e2n;
        pe1v = pe2v; pe2v = peT;
    }
#undef PCLAMP
}

extern "C" void kernel_launch(void* const* d_in, const int* in_sizes, int n_in,
                              void* d_out, int out_size, void* d_ws, size_t ws_size,
                              hipStream_t stream)
{
    const float* H   = (const float*)d_in[0];
    const int*   EI  = (const int*)d_in[1];
    const float* E   = (const float*)d_in[2];
    const float* W   = (const float*)d_in[3];
    const float* We  = (const float*)d_in[4];
    const float* att = (const float*)d_in[5];
    float* out = (float*)d_out;

    // workspace layout (~33 MB); all segments 16B-aligned
    float* HT        = (float*)d_ws;                          // 6.4M f32
    int2*  perm      = (int2*)(HT + (size_t)N_NODES * F_TOT); // 800k int2
    int*   deg       = (int*)(perm + N_EDGES);                // 50k
    int*   row_start = deg + N_NODES;                         // 50004 (padded)
    int*   cursor    = row_start + N_NODES + 4;               // 50k

    hipMemsetAsync(deg, 0, N_NODES * sizeof(int), stream);

    k_pre<<<512, 256, 0, stream>>>(H, W, HT, EI, deg);
    k_scan<<<1, 1024, 0, stream>>>(deg, row_start, cursor);
    k_permute<<<(N_EDGES + 255) / 256, 256, 0, stream>>>(EI, cursor, perm);
    k_fused<<<1024, 256, 0, stream>>>(E, We, att, HT, perm, row_start, out);
}